// Round 5
// baseline (363.072 us; speedup 1.0000x reference)
//
#include <hip/hip_runtime.h>
#include <hip/hip_bf16.h>

using u16 = unsigned short;
using u32 = unsigned int;
using short8 = __attribute__((ext_vector_type(8))) short;  // 8 bf16
using f32x4  = __attribute__((ext_vector_type(4))) float;
using u32x4  = __attribute__((ext_vector_type(4))) u32;
using u32x2  = __attribute__((ext_vector_type(2))) u32;

union V16 { u32x4 u; short8 s; };

__device__ __forceinline__ u16 f2b(float f) {
  u32 u = __float_as_uint(f);
  u32 r = (u + 0x7FFFu + ((u >> 16) & 1u)) >> 16;
  return (u16)r;
}
__device__ __forceinline__ u32 pk2(u16 a, u16 b) {
  return (u32)a | ((u32)b << 16);
}
// packed f32->bf16 pair (RNE), single VOP3 instr (no builtin on gfx950)
__device__ __forceinline__ u32 cvtpk(float lo, float hi) {
  u32 r;
  asm("v_cvt_pk_bf16_f32 %0, %1, %2" : "=v"(r) : "v"(lo), "v"(hi));
  return r;
}

// ---------------------------------------------------------------------------
// Kernel 1: weight transpose + f32->bf16 convert.  out[n][k] = in[k][n]
// ---------------------------------------------------------------------------
__global__ __launch_bounds__(256) void wconv(
    const float* __restrict__ Wq, const float* __restrict__ Wk,
    const float* __restrict__ Wv, const float* __restrict__ Wo,
    u16* __restrict__ Wt, u16* __restrict__ WoT)
{
  __shared__ u16 t_[32][33];
  const int zz = blockIdx.z;
  const float* src = (zz == 0) ? Wq : (zz == 1) ? Wk : (zz == 2) ? Wv : Wo;
  u16* dst = (zz < 3) ? (Wt + (size_t)zz * 1048576) : WoT;
  const int n0 = blockIdx.x * 32, k0 = blockIdx.y * 32;
  const int tx = threadIdx.x, ty = threadIdx.y;
#pragma unroll
  for (int r = ty; r < 32; r += 8)
    t_[tx][r] = f2b(src[(size_t)(k0 + r) * 1024 + n0 + tx]);
  __syncthreads();
#pragma unroll
  for (int r = ty; r < 32; r += 8)
    dst[(size_t)(n0 + r) * 1024 + k0 + tx] = t_[r][tx];
}

// ---------------------------------------------------------------------------
// Kernel 1b: mask -> additive f32 bias (0 or -1e30), into dead Wt region.
// ---------------------------------------------------------------------------
__global__ __launch_bounds__(256) void mkbias(
    const int* __restrict__ mask, float* __restrict__ mb)
{
  const int i = blockIdx.x * 256 + threadIdx.x;  // 4096 total
  mb[i] = mask[i] ? 0.f : -1e30f;
}

// ---------------------------------------------------------------------------
// Kernel 2: QKV projection GEMM.  C = A(f32)[4096x1024] @ W[1024x1024]
// Q,K -> [b][h][n][64]; V -> TRANSPOSED [b][h][d][n] (feeds attn PV
// A-fragment as contiguous 16B global loads -> attn needs no LDS at all).
// ---------------------------------------------------------------------------
#define LDT 56  // padded LDS row stride (ushorts): 112B -> 2-way bank alias (free)

__global__ __launch_bounds__(256) void gemm_qkv_k(
    const float* __restrict__ Aq, const float* __restrict__ Ak, const float* __restrict__ Av,
    const u16* __restrict__ Wt,
    u16* __restrict__ Qw, u16* __restrict__ Kw, u16* __restrict__ Vw)
{
  const int z = blockIdx.z;
  const float* A = (z == 0) ? Aq : (z == 1) ? Ak : Av;
  const u16* B = Wt + (size_t)z * 1048576;
  u16* O = (z == 0) ? Qw : (z == 1) ? Kw : Vw;

  __shared__ u16 As[128 * LDT];
  __shared__ u16 Bs[128 * LDT];

  const int tid = threadIdx.x;
  const int w = tid >> 6, l = tid & 63, lg = l >> 4, ll = l & 15;
  const int wr = w >> 1, wc = w & 1;
  const int m0 = blockIdx.y * 128, n0 = blockIdx.x * 128;
  const int srow = tid >> 1, shalf = tid & 1;

  f32x4 acc[4][4];
#pragma unroll
  for (int i = 0; i < 4; ++i)
#pragma unroll
    for (int t = 0; t < 4; ++t)
      acc[i][t] = (f32x4){0.f, 0.f, 0.f, 0.f};

  for (int kt = 0; kt < 32; ++kt) {
    __syncthreads();
    {
      const f32x4* ap = (const f32x4*)(A + (size_t)(m0 + srow) * 1024 + kt * 32 + shalf * 16);
      f32x4 x0 = ap[0], x1 = ap[1], x2 = ap[2], x3 = ap[3];
      u32x4 u0, u1;
      u0[0] = pk2(f2b(x0[0]), f2b(x0[1])); u0[1] = pk2(f2b(x0[2]), f2b(x0[3]));
      u0[2] = pk2(f2b(x1[0]), f2b(x1[1])); u0[3] = pk2(f2b(x1[2]), f2b(x1[3]));
      u1[0] = pk2(f2b(x2[0]), f2b(x2[1])); u1[1] = pk2(f2b(x2[2]), f2b(x2[3]));
      u1[2] = pk2(f2b(x3[0]), f2b(x3[1])); u1[3] = pk2(f2b(x3[2]), f2b(x3[3]));
      u32x4* da = (u32x4*)&As[srow * LDT + shalf * 16];
      da[0] = u0; da[1] = u1;
      const u32x4* bp = (const u32x4*)(B + (size_t)(n0 + srow) * 1024 + kt * 32 + shalf * 16);
      u32x4* db = (u32x4*)&Bs[srow * LDT + shalf * 16];
      db[0] = bp[0]; db[1] = bp[1];
    }
    __syncthreads();
    short8 af[4], bf[4];
#pragma unroll
    for (int i = 0; i < 4; ++i) {
      V16 v; v.u = *(const u32x4*)&As[(wr * 64 + i * 16 + ll) * LDT + lg * 8];
      af[i] = v.s;
    }
#pragma unroll
    for (int t = 0; t < 4; ++t) {
      V16 v; v.u = *(const u32x4*)&Bs[(wc * 64 + t * 16 + ll) * LDT + lg * 8];
      bf[t] = v.s;
    }
#pragma unroll
    for (int i = 0; i < 4; ++i)
#pragma unroll
      for (int t = 0; t < 4; ++t)
        acc[i][t] = __builtin_amdgcn_mfma_f32_16x16x32_bf16(af[i], bf[t], acc[i][t], 0, 0, 0);
  }

  if (z == 2) {
    // V^T epilogue: Vw[((b*16+h)*64 + d)*2048 + pos], 4 consecutive pos -> 8B write
#pragma unroll
    for (int i = 0; i < 4; ++i)
#pragma unroll
      for (int t = 0; t < 4; ++t) {
        const int n = n0 + wc * 64 + t * 16 + ll;
        const int h = n >> 6, dd = n & 63;
        const int mbase = m0 + wr * 64 + i * 16 + lg * 4;
        const int bb = mbase >> 11, pos = mbase & 2047;
        u32x2 wv;
        wv[0] = pk2(f2b(acc[i][t][0]), f2b(acc[i][t][1]));
        wv[1] = pk2(f2b(acc[i][t][2]), f2b(acc[i][t][3]));
        *(u32x2*)&O[((size_t)(bb * 16 + h) * 64 + dd) * 2048 + pos] = wv;
      }
  } else {
#pragma unroll
    for (int i = 0; i < 4; ++i)
#pragma unroll
      for (int t = 0; t < 4; ++t) {
        const int n = n0 + wc * 64 + t * 16 + ll;
        const int h = n >> 6, dd = n & 63;
#pragma unroll
        for (int j = 0; j < 4; ++j) {
          const int m = m0 + wr * 64 + i * 16 + lg * 4 + j;
          const int bb = m >> 11, pos = m & 2047;
          O[((size_t)(bb * 16 + h) * 2048 + pos) * 64 + dd] = f2b(acc[i][t][j]);
        }
      }
  }
}

// ---------------------------------------------------------------------------
// Kernel 3: flash attention, swapped-operand, ZERO LDS / ZERO barriers.
// grid (32 qblocks, 16 heads, 2 batch), 4 independent waves per block.
// S^T = mfma(A=K_perm, B=Q): lane (lg,ll) holds scores for q=ll, keys
// pi(t,m) = (t>>1)*32 + lg*8 + (t&1)*4 + j -> lane's P values are exactly the
// PV B-fragment (k=lg*8..+7) in identity key order.  PV: o^T = mfma(A=V^T, B=P)
// with V^T[d][n] read as contiguous 16B global loads (pre-transposed by the
// V-projection epilogue).  K/V^T tiles are L2-resident (256KB/head, 32 blocks
// share).  No syncs -> compiler pipelines loads across iterations.
// ---------------------------------------------------------------------------
__global__ __launch_bounds__(256) void attn_k(
    const u16* __restrict__ Q, const u16* __restrict__ K, const u16* __restrict__ VT,
    const float* __restrict__ mbias, u16* __restrict__ X)
{
  const int tid = threadIdx.x;
  const int w = tid >> 6, l = tid & 63, lg = l >> 4, ll = l & 15;
  const int qb = blockIdx.x, h = blockIdx.y, b = blockIdx.z;
  const size_t base = (size_t)(b * 16 + h) * 2048 * 64;  // same for K and V^T
  const int q0 = qb * 64 + w * 16;
  const int kr = ((ll >> 2) << 3) | (ll & 3);  // A-row permutation base

  // Q fragments (B-operand): lane holds Q[q0+ll][d = s*32 + lg*8 + i]
  short8 aq[2];
#pragma unroll
  for (int s = 0; s < 2; ++s) {
    V16 v; v.u = *(const u32x4*)&Q[base + (size_t)(q0 + ll) * 64 + s * 32 + lg * 8];
    aq[s] = v.s;
  }

  float mrow = -1e30f, lrow = 0.f;
  f32x4 o[4];  // o[td][j] = o^T[d' = td*16+lg*4+j][q = ll]
#pragma unroll
  for (int td = 0; td < 4; ++td) o[td] = (f32x4){0.f, 0.f, 0.f, 0.f};

#pragma unroll 2
  for (int kt = 0; kt < 32; ++kt) {
    const int j0 = kt * 64;

    // QK^T swapped: S^T tile t = mfma(A = K rows pi(t,m), B = Q)
    f32x4 sc[4];
#pragma unroll
    for (int t = 0; t < 4; ++t) {
      const int row = j0 + ((t >> 1) << 5) + ((t & 1) << 2) + kr;
      const u16* kp = &K[base + (size_t)row * 64];
      short8 bk0, bk1;
      { V16 v; v.u = *(const u32x4*)&kp[lg * 8];      bk0 = v.s; }
      { V16 v; v.u = *(const u32x4*)&kp[32 + lg * 8]; bk1 = v.s; }
      f32x4 a = (f32x4){0.f, 0.f, 0.f, 0.f};
      a = __builtin_amdgcn_mfma_f32_16x16x32_bf16(bk0, aq[0], a, 0, 0, 0);
      a = __builtin_amdgcn_mfma_f32_16x16x32_bf16(bk1, aq[1], a, 0, 0, 0);
      const f32x4 mb = *(const f32x4*)&mbias[b * 2048 + j0 + ((t >> 1) << 5) + ((t & 1) << 2) + (lg << 3)];
#pragma unroll
      for (int j = 0; j < 4; ++j)
        sc[t][j] = a[j] * 0.125f + mb[j];
    }

    // online softmax: per-lane scalar state for q = ll
    f32x4 mx4;
#pragma unroll
    for (int j = 0; j < 4; ++j)
      mx4[j] = fmaxf(fmaxf(sc[0][j], sc[1][j]), fmaxf(sc[2][j], sc[3][j]));
    float rm = fmaxf(fmaxf(mx4[0], mx4[1]), fmaxf(mx4[2], mx4[3]));
    rm = fmaxf(rm, __shfl_xor(rm, 16));
    rm = fmaxf(rm, __shfl_xor(rm, 32));

    const float mn = fmaxf(mrow, rm);
    const float alpha = __expf(mrow - mn);
    mrow = mn;

    f32x4 p4[4];
    f32x4 s4 = (f32x4){0.f, 0.f, 0.f, 0.f};
#pragma unroll
    for (int t = 0; t < 4; ++t) {
#pragma unroll
      for (int j = 0; j < 4; ++j) {
        p4[t][j] = __expf(sc[t][j] - mn);
        s4[j] += p4[t][j];
      }
    }
    float rs = (s4[0] + s4[1]) + (s4[2] + s4[3]);
    rs += __shfl_xor(rs, 16);
    rs += __shfl_xor(rs, 32);
    lrow = lrow * alpha + rs;
#pragma unroll
    for (int td = 0; td < 4; ++td)
#pragma unroll
      for (int j = 0; j < 4; ++j)
        o[td][j] *= alpha;

    // PV: o^T = mfma(A = V^T from global, B = P-from-registers)
#pragma unroll
    for (int s = 0; s < 2; ++s) {
      V16 pb;
      pb.u[0] = cvtpk(p4[2 * s][0], p4[2 * s][1]);
      pb.u[1] = cvtpk(p4[2 * s][2], p4[2 * s][3]);
      pb.u[2] = cvtpk(p4[2 * s + 1][0], p4[2 * s + 1][1]);
      pb.u[3] = cvtpk(p4[2 * s + 1][2], p4[2 * s + 1][3]);
#pragma unroll
      for (int td = 0; td < 4; ++td) {
        V16 v; v.u = *(const u32x4*)&VT[base + (size_t)(td * 16 + ll) * 2048 + j0 + s * 32 + lg * 8];
        o[td] = __builtin_amdgcn_mfma_f32_16x16x32_bf16(v.s, pb.s, o[td], 0, 0, 0);
      }
    }
  }

  // normalize + write X[b][q][h*64+d] bf16 (8B per td)
  const float inv = 1.f / lrow;
  u16* xp = &X[((size_t)(b * 2048 + q0 + ll)) * 1024 + h * 64 + lg * 4];
#pragma unroll
  for (int td = 0; td < 4; ++td) {
    u32x2 wv;
    wv[0] = cvtpk(o[td][0] * inv, o[td][1] * inv);
    wv[1] = cvtpk(o[td][2] * inv, o[td][3] * inv);
    *(u32x2*)&xp[td * 16] = wv;
  }
}

// ---------------------------------------------------------------------------
// Kernel 4: output GEMM + bias.  out = X(bf16)[4096x1024] @ Wo + bo, f32 out.
// ---------------------------------------------------------------------------
__global__ __launch_bounds__(256) void gemm_out_k(
    const u16* __restrict__ Xw, const u16* __restrict__ WoT,
    const float* __restrict__ bo, float* __restrict__ out)
{
  __shared__ u16 As[128 * LDT];
  __shared__ u16 Bs[128 * LDT];

  const int tid = threadIdx.x;
  const int w = tid >> 6, l = tid & 63, lg = l >> 4, ll = l & 15;
  const int wr = w >> 1, wc = w & 1;
  const int m0 = blockIdx.y * 128, n0 = blockIdx.x * 128;
  const int srow = tid >> 1, shalf = tid & 1;

  f32x4 acc[4][4];
#pragma unroll
  for (int i = 0; i < 4; ++i)
#pragma unroll
    for (int t = 0; t < 4; ++t)
      acc[i][t] = (f32x4){0.f, 0.f, 0.f, 0.f};

  for (int kt = 0; kt < 32; ++kt) {
    __syncthreads();
    {
      const u32x4* ap = (const u32x4*)(Xw + (size_t)(m0 + srow) * 1024 + kt * 32 + shalf * 16);
      u32x4* da = (u32x4*)&As[srow * LDT + shalf * 16];
      da[0] = ap[0]; da[1] = ap[1];
      const u32x4* bp = (const u32x4*)(WoT + (size_t)(n0 + srow) * 1024 + kt * 32 + shalf * 16);
      u32x4* db = (u32x4*)&Bs[srow * LDT + shalf * 16];
      db[0] = bp[0]; db[1] = bp[1];
    }
    __syncthreads();
    short8 af[4], bf[4];
#pragma unroll
    for (int i = 0; i < 4; ++i) {
      V16 v; v.u = *(const u32x4*)&As[(wr * 64 + i * 16 + ll) * LDT + lg * 8];
      af[i] = v.s;
    }
#pragma unroll
    for (int t = 0; t < 4; ++t) {
      V16 v; v.u = *(const u32x4*)&Bs[(wc * 64 + t * 16 + ll) * LDT + lg * 8];
      bf[t] = v.s;
    }
#pragma unroll
    for (int i = 0; i < 4; ++i)
#pragma unroll
      for (int t = 0; t < 4; ++t)
        acc[i][t] = __builtin_amdgcn_mfma_f32_16x16x32_bf16(af[i], bf[t], acc[i][t], 0, 0, 0);
  }

#pragma unroll
  for (int i = 0; i < 4; ++i)
#pragma unroll
    for (int t = 0; t < 4; ++t) {
      const int n = n0 + wc * 64 + t * 16 + ll;
      const float bv = bo[n];
#pragma unroll
      for (int j = 0; j < 4; ++j) {
        const int m = m0 + wr * 64 + i * 16 + lg * 4 + j;
        out[(size_t)m * 1024 + n] = acc[i][t][j] + bv;
      }
    }
}

// ---------------------------------------------------------------------------
extern "C" void kernel_launch(void* const* d_in, const int* in_sizes, int n_in,
                              void* d_out, int out_size, void* d_ws, size_t ws_size,
                              hipStream_t stream) {
  const float* qry = (const float*)d_in[0];
  const float* key = (const float*)d_in[1];
  const float* val = (const float*)d_in[2];
  const int* mask  = (const int*)d_in[3];
  const float* Wq  = (const float*)d_in[4];
  const float* Wk  = (const float*)d_in[5];
  const float* Wv  = (const float*)d_in[6];
  const float* Wo  = (const float*)d_in[7];
  const float* bo  = (const float*)d_in[8];
  float* out = (float*)d_out;

  char* ws = (char*)d_ws;
  u16* Wt  = (u16*)(ws);                 // 3 x 1024x1024 bf16 = 6 MB
  u16* WoT = (u16*)(ws + 6291456);       // 2 MB
  u16* Qw  = (u16*)(ws + 8388608);       // 8 MB  [b][h][n][64]
  u16* Kw  = (u16*)(ws + 16777216);      // 8 MB  [b][h][n][64]
  u16* Vw  = (u16*)(ws + 25165824);      // 8 MB  [b][h][64][n]  (V^T)
  u16* Xw  = (u16*)(ws + 33554432);      // 8 MB  [b*n][1024]
  float* mbias = (float*)(ws);           // 16 KB, reuses Wt region after gemm_qkv

  wconv<<<dim3(32, 32, 4), dim3(32, 8, 1), 0, stream>>>(Wq, Wk, Wv, Wo, Wt, WoT);
  gemm_qkv_k<<<dim3(8, 32, 3), 256, 0, stream>>>(qry, key, val, Wt, Qw, Kw, Vw);
  mkbias<<<dim3(16, 1, 1), 256, 0, stream>>>(mask, mbias);
  attn_k<<<dim3(32, 16, 2), 256, 0, stream>>>(Qw, Kw, Vw, mbias, Xw);
  gemm_out_k<<<dim3(8, 32, 1), 256, 0, stream>>>(Xw, WoT, bo, out);
}

// Round 6
// 191.578 us; speedup vs baseline: 1.8952x; 1.8952x over previous
//
#include <hip/hip_runtime.h>
#include <hip/hip_bf16.h>

using u16 = unsigned short;
using u32 = unsigned int;
using short8 = __attribute__((ext_vector_type(8))) short;  // 8 bf16
using f32x4  = __attribute__((ext_vector_type(4))) float;
using u32x4  = __attribute__((ext_vector_type(4))) u32;
using u32x2  = __attribute__((ext_vector_type(2))) u32;

union V16 { u32x4 u; short8 s; };

__device__ __forceinline__ u16 f2b(float f) {
  u32 u = __float_as_uint(f);
  u32 r = (u + 0x7FFFu + ((u >> 16) & 1u)) >> 16;
  return (u16)r;
}
__device__ __forceinline__ u32 pk2(u16 a, u16 b) {
  return (u32)a | ((u32)b << 16);
}
// packed f32->bf16 pair (RNE), single VOP3 instr (no builtin on gfx950)
__device__ __forceinline__ u32 cvtpk(float lo, float hi) {
  u32 r;
  asm("v_cvt_pk_bf16_f32 %0, %1, %2" : "=v"(r) : "v"(lo), "v"(hi));
  return r;
}

// ---------------------------------------------------------------------------
// Kernel 1: weight transpose + f32->bf16 convert.  out[n][k] = in[k][n]
// ---------------------------------------------------------------------------
__global__ __launch_bounds__(256) void wconv(
    const float* __restrict__ Wq, const float* __restrict__ Wk,
    const float* __restrict__ Wv, const float* __restrict__ Wo,
    u16* __restrict__ Wt, u16* __restrict__ WoT)
{
  __shared__ u16 t_[32][33];
  const int zz = blockIdx.z;
  const float* src = (zz == 0) ? Wq : (zz == 1) ? Wk : (zz == 2) ? Wv : Wo;
  u16* dst = (zz < 3) ? (Wt + (size_t)zz * 1048576) : WoT;
  const int n0 = blockIdx.x * 32, k0 = blockIdx.y * 32;
  const int tx = threadIdx.x, ty = threadIdx.y;
#pragma unroll
  for (int r = ty; r < 32; r += 8)
    t_[tx][r] = f2b(src[(size_t)(k0 + r) * 1024 + n0 + tx]);
  __syncthreads();
#pragma unroll
  for (int r = ty; r < 32; r += 8)
    dst[(size_t)(n0 + r) * 1024 + k0 + tx] = t_[r][tx];
}

// ---------------------------------------------------------------------------
// Kernel 1b: mask -> additive f32 bias (0 or -1e30), into dead Wt region.
// ---------------------------------------------------------------------------
__global__ __launch_bounds__(256) void mkbias(
    const int* __restrict__ mask, float* __restrict__ mb)
{
  const int i = blockIdx.x * 256 + threadIdx.x;  // 4096 total
  mb[i] = mask[i] ? 0.f : -1e30f;
}

// ---------------------------------------------------------------------------
// Kernel 2: QKV projection GEMM.  C = A(f32)[4096x1024] @ W[1024x1024]
// Q -> [b][h][n][64].
// K,V -> FRAGMENT-IMAGE tiled layouts: per (b,h,kt) a 4096-u16 tile holding
// bytes in exact MFMA-fragment consumption order (chunk*512 + lane*8 + e), so
// the attention kernel stages tiles with purely linear, conflict-free copies.
//   K image: chunk (t*2+s), lane lg*16+ll, elem e  <->  K[pi(t,ll)][s*32+lg*8+e]
//            pi(t,m) = (t>>1)*32 + (t&1)*4 + (m>>2)*8 + (m&3)
//   V image: chunk (s*4+td), lane lg*16+ll, elem e <->  V[key=s*32+lg*8+e][d=td*16+ll]
// ---------------------------------------------------------------------------
#define LDT 56  // padded LDS row stride (ushorts): 112B -> 2-way bank alias (free)

__global__ __launch_bounds__(256) void gemm_qkv_k(
    const float* __restrict__ Aq, const float* __restrict__ Ak, const float* __restrict__ Av,
    const u16* __restrict__ Wt,
    u16* __restrict__ Qw, u16* __restrict__ Kw, u16* __restrict__ Vw)
{
  const int z = blockIdx.z;
  const float* A = (z == 0) ? Aq : (z == 1) ? Ak : Av;
  const u16* B = Wt + (size_t)z * 1048576;
  u16* O = (z == 0) ? Qw : (z == 1) ? Kw : Vw;

  __shared__ u16 As[128 * LDT];
  __shared__ u16 Bs[128 * LDT];

  const int tid = threadIdx.x;
  const int w = tid >> 6, l = tid & 63, lg = l >> 4, ll = l & 15;
  const int wr = w >> 1, wc = w & 1;
  const int m0 = blockIdx.y * 128, n0 = blockIdx.x * 128;
  const int srow = tid >> 1, shalf = tid & 1;

  f32x4 acc[4][4];
#pragma unroll
  for (int i = 0; i < 4; ++i)
#pragma unroll
    for (int t = 0; t < 4; ++t)
      acc[i][t] = (f32x4){0.f, 0.f, 0.f, 0.f};

  for (int kt = 0; kt < 32; ++kt) {
    __syncthreads();
    {
      const f32x4* ap = (const f32x4*)(A + (size_t)(m0 + srow) * 1024 + kt * 32 + shalf * 16);
      f32x4 x0 = ap[0], x1 = ap[1], x2 = ap[2], x3 = ap[3];
      u32x4 u0, u1;
      u0[0] = pk2(f2b(x0[0]), f2b(x0[1])); u0[1] = pk2(f2b(x0[2]), f2b(x0[3]));
      u0[2] = pk2(f2b(x1[0]), f2b(x1[1])); u0[3] = pk2(f2b(x1[2]), f2b(x1[3]));
      u1[0] = pk2(f2b(x2[0]), f2b(x2[1])); u1[1] = pk2(f2b(x2[2]), f2b(x2[3]));
      u1[2] = pk2(f2b(x3[0]), f2b(x3[1])); u1[3] = pk2(f2b(x3[2]), f2b(x3[3]));
      u32x4* da = (u32x4*)&As[srow * LDT + shalf * 16];
      da[0] = u0; da[1] = u1;
      const u32x4* bp = (const u32x4*)(B + (size_t)(n0 + srow) * 1024 + kt * 32 + shalf * 16);
      u32x4* db = (u32x4*)&Bs[srow * LDT + shalf * 16];
      db[0] = bp[0]; db[1] = bp[1];
    }
    __syncthreads();
    short8 af[4], bf[4];
#pragma unroll
    for (int i = 0; i < 4; ++i) {
      V16 v; v.u = *(const u32x4*)&As[(wr * 64 + i * 16 + ll) * LDT + lg * 8];
      af[i] = v.s;
    }
#pragma unroll
    for (int t = 0; t < 4; ++t) {
      V16 v; v.u = *(const u32x4*)&Bs[(wc * 64 + t * 16 + ll) * LDT + lg * 8];
      bf[t] = v.s;
    }
#pragma unroll
    for (int i = 0; i < 4; ++i)
#pragma unroll
      for (int t = 0; t < 4; ++t)
        acc[i][t] = __builtin_amdgcn_mfma_f32_16x16x32_bf16(af[i], bf[t], acc[i][t], 0, 0, 0);
  }

  if (z == 0) {
    // Q: [b][h][n][64]
#pragma unroll
    for (int i = 0; i < 4; ++i)
#pragma unroll
      for (int te = 0; te < 4; ++te) {
        const int n = n0 + wc * 64 + te * 16 + ll;
        const int h = n >> 6, dd = n & 63;
#pragma unroll
        for (int j = 0; j < 4; ++j) {
          const int m = m0 + wr * 64 + i * 16 + lg * 4 + j;
          const int bb = m >> 11, pos = m & 2047;
          O[((size_t)(bb * 16 + h) * 2048 + pos) * 64 + dd] = f2b(acc[i][te][j]);
        }
      }
  } else if (z == 1) {
    // K fragment image: invert pi -> (t,ll); chunk t*2+s, lane lgk*16+ll, elem e
#pragma unroll
    for (int i = 0; i < 4; ++i)
#pragma unroll
      for (int te = 0; te < 4; ++te) {
        const int n = n0 + wc * 64 + te * 16 + ll;
        const int h = n >> 6, dd = n & 63;
        const int s = dd >> 5, lgk = (dd >> 3) & 3, e = dd & 7;
#pragma unroll
        for (int j = 0; j < 4; ++j) {
          const int m = m0 + wr * 64 + i * 16 + lg * 4 + j;
          const int bb = m >> 11, pos = m & 2047;
          const int kt2 = pos >> 6, r = pos & 63;
          const int t2 = ((r >> 5) << 1) | ((r >> 2) & 1);
          const int ll2 = (((r >> 3) & 3) << 2) | (r & 3);
          O[((size_t)((bb * 16 + h) * 32 + kt2)) * 4096 + (t2 * 2 + s) * 512 + (lgk * 16 + ll2) * 8 + e]
              = f2b(acc[i][te][j]);
        }
      }
  } else {
    // V fragment image: chunk s*4+td, lane lgv*16+llv, elems e0..e0+3 (8B store)
#pragma unroll
    for (int i = 0; i < 4; ++i)
#pragma unroll
      for (int te = 0; te < 4; ++te) {
        const int n = n0 + wc * 64 + te * 16 + ll;
        const int h = n >> 6, dd = n & 63;
        const int td = dd >> 4, llv = dd & 15;
        const int mb0 = m0 + wr * 64 + i * 16 + lg * 4;   // j = 0
        const int bb = mb0 >> 11, pos = mb0 & 2047;
        const int kt2 = pos >> 6, kk = pos & 63;
        const int s = kk >> 5, lgv = (kk >> 3) & 3, e0 = kk & 7;
        u32x2 wv;
        wv[0] = pk2(f2b(acc[i][te][0]), f2b(acc[i][te][1]));
        wv[1] = pk2(f2b(acc[i][te][2]), f2b(acc[i][te][3]));
        *(u32x2*)&O[((size_t)((bb * 16 + h) * 32 + kt2)) * 4096 + (s * 4 + td) * 512 + (lgv * 16 + llv) * 8 + e0]
            = wv;
      }
  }
}

// ---------------------------------------------------------------------------
// Kernel 3: flash attention with fragment-image LDS staging (T14 async split).
// grid (32 qblocks, 16 heads, 2 batch), 4 waves.  Per K-tile iteration:
//   barrier; ds_write staged regs (16KB tile, 4 chunks/wave, all linear);
//   issue next tile's global loads (hide under compute); barrier;
//   ds_read fragments (b128, lane-linear, conflict-free); QK^T, softmax, PV.
// K/V tiles shared by all 4 waves -> 4x less L2 traffic than per-wave loads.
// ---------------------------------------------------------------------------
__global__ __launch_bounds__(256) void attn_k(
    const u16* __restrict__ Q, const u16* __restrict__ Kt, const u16* __restrict__ Vt,
    const float* __restrict__ mbias, u16* __restrict__ X)
{
  __shared__ u16 Ls[8192];  // [0,4096): K image tile; [4096,8192): V image tile

  const int tid = threadIdx.x;
  const int w = tid >> 6, l = tid & 63, lg = l >> 4, ll = l & 15;
  const int qb = blockIdx.x, h = blockIdx.y, b = blockIdx.z;
  const size_t qbase = (size_t)(b * 16 + h) * 2048 * 64;
  const size_t tbase = (size_t)((b * 16 + h) * 32) * 4096;
  const int q0 = qb * 64 + w * 16;

  // Q fragments (B-operand): lane holds Q[q0+ll][d = s*32 + lg*8 + e]
  short8 aq[2];
#pragma unroll
  for (int s = 0; s < 2; ++s) {
    V16 v; v.u = *(const u32x4*)&Q[qbase + (size_t)(q0 + ll) * 64 + s * 32 + lg * 8];
    aq[s] = v.s;
  }

  float mrow = -1e30f, lrow = 0.f;
  f32x4 o[4];  // o[td][j] = O^T[d = td*16+lg*4+j][q = ll]
#pragma unroll
  for (int td = 0; td < 4; ++td) o[td] = (f32x4){0.f, 0.f, 0.f, 0.f};

  // staging: wave w owns chunks w*4 .. w*4+3 (of 16; 0-7 K image, 8-15 V image)
  u32x4 rg[4];
#pragma unroll
  for (int q = 0; q < 4; ++q) {
    const int c = w * 4 + q;
    const u16* src = (c < 8) ? Kt : Vt;
    rg[q] = *(const u32x4*)&src[tbase + (c & 7) * 512 + l * 8];
  }

  for (int kt = 0; kt < 32; ++kt) {
    const int j0 = kt * 64;
    __syncthreads();   // previous iteration's LDS reads complete

    // write staged tile (conflict-free b128, lane-linear)
#pragma unroll
    for (int q = 0; q < 4; ++q) {
      const int c = w * 4 + q;
      *(u32x4*)&Ls[c * 512 + l * 8] = rg[q];
    }
    // issue next tile's loads; latency hides under compute below
    if (kt + 1 < 32) {
#pragma unroll
      for (int q = 0; q < 4; ++q) {
        const int c = w * 4 + q;
        const u16* src = (c < 8) ? Kt : Vt;
        rg[q] = *(const u32x4*)&src[tbase + (size_t)(kt + 1) * 4096 + (c & 7) * 512 + l * 8];
      }
    }
    __syncthreads();   // staged tile visible

    // QK^T swapped: S^T tile t = mfma(A = K image chunk, B = Q)
    f32x4 sc[4];
#pragma unroll
    for (int t = 0; t < 4; ++t) {
      short8 bk0, bk1;
      { V16 v; v.u = *(const u32x4*)&Ls[(t * 2 + 0) * 512 + l * 8]; bk0 = v.s; }
      { V16 v; v.u = *(const u32x4*)&Ls[(t * 2 + 1) * 512 + l * 8]; bk1 = v.s; }
      f32x4 a = (f32x4){0.f, 0.f, 0.f, 0.f};
      a = __builtin_amdgcn_mfma_f32_16x16x32_bf16(bk0, aq[0], a, 0, 0, 0);
      a = __builtin_amdgcn_mfma_f32_16x16x32_bf16(bk1, aq[1], a, 0, 0, 0);
      const f32x4 mb = *(const f32x4*)&mbias[b * 2048 + j0 + ((t >> 1) << 5) + ((t & 1) << 2) + (lg << 3)];
#pragma unroll
      for (int j = 0; j < 4; ++j)
        sc[t][j] = a[j] * 0.125f + mb[j];
    }

    // online softmax: per-lane scalar state for q = ll
    f32x4 mx4;
#pragma unroll
    for (int j = 0; j < 4; ++j)
      mx4[j] = fmaxf(fmaxf(sc[0][j], sc[1][j]), fmaxf(sc[2][j], sc[3][j]));
    float rm = fmaxf(fmaxf(mx4[0], mx4[1]), fmaxf(mx4[2], mx4[3]));
    rm = fmaxf(rm, __shfl_xor(rm, 16));
    rm = fmaxf(rm, __shfl_xor(rm, 32));

    const float mn = fmaxf(mrow, rm);
    const float alpha = __expf(mrow - mn);
    mrow = mn;

    f32x4 p4[4];
    f32x4 s4 = (f32x4){0.f, 0.f, 0.f, 0.f};
#pragma unroll
    for (int t = 0; t < 4; ++t) {
#pragma unroll
      for (int j = 0; j < 4; ++j) {
        p4[t][j] = __expf(sc[t][j] - mn);
        s4[j] += p4[t][j];
      }
    }
    float rs = (s4[0] + s4[1]) + (s4[2] + s4[3]);
    rs += __shfl_xor(rs, 16);
    rs += __shfl_xor(rs, 32);
    lrow = lrow * alpha + rs;
#pragma unroll
    for (int td = 0; td < 4; ++td)
#pragma unroll
      for (int j = 0; j < 4; ++j)
        o[td][j] *= alpha;

    // PV: o^T = mfma(A = V image chunk, B = P-from-registers)
#pragma unroll
    for (int s = 0; s < 2; ++s) {
      V16 pb;
      pb.u[0] = cvtpk(p4[2 * s][0], p4[2 * s][1]);
      pb.u[1] = cvtpk(p4[2 * s][2], p4[2 * s][3]);
      pb.u[2] = cvtpk(p4[2 * s + 1][0], p4[2 * s + 1][1]);
      pb.u[3] = cvtpk(p4[2 * s + 1][2], p4[2 * s + 1][3]);
#pragma unroll
      for (int td = 0; td < 4; ++td) {
        V16 v; v.u = *(const u32x4*)&Ls[4096 + (s * 4 + td) * 512 + l * 8];
        o[td] = __builtin_amdgcn_mfma_f32_16x16x32_bf16(v.s, pb.s, o[td], 0, 0, 0);
      }
    }
  }

  // normalize + write X[b][q][h*64+d] bf16 (8B per td)
  const float inv = 1.f / lrow;
  u16* xp = &X[((size_t)(b * 2048 + q0 + ll)) * 1024 + h * 64 + lg * 4];
#pragma unroll
  for (int td = 0; td < 4; ++td) {
    u32x2 wv;
    wv[0] = cvtpk(o[td][0] * inv, o[td][1] * inv);
    wv[1] = cvtpk(o[td][2] * inv, o[td][3] * inv);
    *(u32x2*)&xp[td * 16] = wv;
  }
}

// ---------------------------------------------------------------------------
// Kernel 4: output GEMM + bias.  out = X(bf16)[4096x1024] @ Wo + bo, f32 out.
// ---------------------------------------------------------------------------
__global__ __launch_bounds__(256) void gemm_out_k(
    const u16* __restrict__ Xw, const u16* __restrict__ WoT,
    const float* __restrict__ bo, float* __restrict__ out)
{
  __shared__ u16 As[128 * LDT];
  __shared__ u16 Bs[128 * LDT];

  const int tid = threadIdx.x;
  const int w = tid >> 6, l = tid & 63, lg = l >> 4, ll = l & 15;
  const int wr = w >> 1, wc = w & 1;
  const int m0 = blockIdx.y * 128, n0 = blockIdx.x * 128;
  const int srow = tid >> 1, shalf = tid & 1;

  f32x4 acc[4][4];
#pragma unroll
  for (int i = 0; i < 4; ++i)
#pragma unroll
    for (int t = 0; t < 4; ++t)
      acc[i][t] = (f32x4){0.f, 0.f, 0.f, 0.f};

  for (int kt = 0; kt < 32; ++kt) {
    __syncthreads();
    {
      const u32x4* ap = (const u32x4*)(Xw + (size_t)(m0 + srow) * 1024 + kt * 32 + shalf * 16);
      u32x4* da = (u32x4*)&As[srow * LDT + shalf * 16];
      da[0] = ap[0]; da[1] = ap[1];
      const u32x4* bp = (const u32x4*)(WoT + (size_t)(n0 + srow) * 1024 + kt * 32 + shalf * 16);
      u32x4* db = (u32x4*)&Bs[srow * LDT + shalf * 16];
      db[0] = bp[0]; db[1] = bp[1];
    }
    __syncthreads();
    short8 af[4], bf[4];
#pragma unroll
    for (int i = 0; i < 4; ++i) {
      V16 v; v.u = *(const u32x4*)&As[(wr * 64 + i * 16 + ll) * LDT + lg * 8];
      af[i] = v.s;
    }
#pragma unroll
    for (int t = 0; t < 4; ++t) {
      V16 v; v.u = *(const u32x4*)&Bs[(wc * 64 + t * 16 + ll) * LDT + lg * 8];
      bf[t] = v.s;
    }
#pragma unroll
    for (int i = 0; i < 4; ++i)
#pragma unroll
      for (int t = 0; t < 4; ++t)
        acc[i][t] = __builtin_amdgcn_mfma_f32_16x16x32_bf16(af[i], bf[t], acc[i][t], 0, 0, 0);
  }

#pragma unroll
  for (int i = 0; i < 4; ++i)
#pragma unroll
    for (int t = 0; t < 4; ++t) {
      const int n = n0 + wc * 64 + t * 16 + ll;
      const float bv = bo[n];
#pragma unroll
      for (int j = 0; j < 4; ++j) {
        const int m = m0 + wr * 64 + i * 16 + lg * 4 + j;
        out[(size_t)m * 1024 + n] = acc[i][t][j] + bv;
      }
    }
}

// ---------------------------------------------------------------------------
extern "C" void kernel_launch(void* const* d_in, const int* in_sizes, int n_in,
                              void* d_out, int out_size, void* d_ws, size_t ws_size,
                              hipStream_t stream) {
  const float* qry = (const float*)d_in[0];
  const float* key = (const float*)d_in[1];
  const float* val = (const float*)d_in[2];
  const int* mask  = (const int*)d_in[3];
  const float* Wq  = (const float*)d_in[4];
  const float* Wk  = (const float*)d_in[5];
  const float* Wv  = (const float*)d_in[6];
  const float* Wo  = (const float*)d_in[7];
  const float* bo  = (const float*)d_in[8];
  float* out = (float*)d_out;

  char* ws = (char*)d_ws;
  u16* Wt  = (u16*)(ws);                 // 3 x 1024x1024 bf16 = 6 MB
  u16* WoT = (u16*)(ws + 6291456);       // 2 MB
  u16* Qw  = (u16*)(ws + 8388608);       // 8 MB  [b][h][n][64]
  u16* Kw  = (u16*)(ws + 16777216);      // 8 MB  K fragment-image tiles
  u16* Vw  = (u16*)(ws + 25165824);      // 8 MB  V fragment-image tiles
  u16* Xw  = (u16*)(ws + 33554432);      // 8 MB  [b*n][1024]
  float* mbias = (float*)(ws);           // 16 KB, reuses Wt region after gemm_qkv

  wconv<<<dim3(32, 32, 4), dim3(32, 8, 1), 0, stream>>>(Wq, Wk, Wv, Wo, Wt, WoT);
  gemm_qkv_k<<<dim3(8, 32, 3), 256, 0, stream>>>(qry, key, val, Wt, Qw, Kw, Vw);
  mkbias<<<dim3(16, 1, 1), 256, 0, stream>>>(mask, mbias);
  attn_k<<<dim3(32, 16, 2), 256, 0, stream>>>(Qw, Kw, Vw, mbias, Xw);
  gemm_out_k<<<dim3(8, 32, 1), 256, 0, stream>>>(Xw, WoT, bo, out);
}